// Round 4
// baseline (163.370 us; speedup 1.0000x reference)
//
#include <hip/hip_runtime.h>
#include <hip/hip_bf16.h>

typedef __attribute__((ext_vector_type(8))) short bf16x8;
typedef __attribute__((ext_vector_type(4))) float f32x4;

#define D_K    256
#define WH     784
#define WHH    392
#define P_REAL 511
#define P_PAD  512
#define C_OUT  200
#define NLEAF  512
#define TDEPTH 9

#define NT      32
#define NTILES  13          // 12*32 + 8 tail (clamped duplicate columns)
#define XS_STRIDE 288       // ushorts per LDS n-row

// workspace offsets (bytes)
#define WS_PROTO 0
#define WS_P2    (P_PAD*D_K*2)            // 262144
#define WS_PM    (WS_P2 + P_PAD*4)        // 264192  pm[128][2][512] f32
#define WS_DS    (WS_PM + 128*2*P_PAD*4)  // 788480
// total: 788480 + 512*200*4 = 1198080 bytes

static __device__ __forceinline__ unsigned short f2bf(float x) {
    union { float f; unsigned int u; } v; v.f = x;
    unsigned int r = v.u + 0x7FFFu + ((v.u >> 16) & 1u);   // RNE
    return (unsigned short)(r >> 16);
}

// swizzled LDS index (ushort units): XOR row bits into byte bits 4..6;
// bijective per row, keeps 8B-write / 16B-read alignment
static __device__ __forceinline__ int xs_idx(int n, int k) {
    return (n * XS_STRIDE + k) ^ ((n & 0x1C) << 1);
}

// --- fused prep (proto -> bf16(-2p) + p2) and softmax(leaf_params) --------
__global__ __launch_bounds__(64)
void prep2_kernel(const float* __restrict__ protos, const float* __restrict__ lp,
                  unsigned short* __restrict__ pb, float* __restrict__ p2,
                  float* __restrict__ ds) {
    int bid = blockIdx.x;
    int l = threadIdx.x;
    if (bid < P_PAD) {
        int p = bid;
        f32x4 v = {0.f, 0.f, 0.f, 0.f};
        if (p < P_REAL)
            v = *reinterpret_cast<const f32x4*>(protos + (size_t)p * D_K + 4 * l);
        ushort4 w;
        w.x = f2bf(-2.f * v[0]); w.y = f2bf(-2.f * v[1]);
        w.z = f2bf(-2.f * v[2]); w.w = f2bf(-2.f * v[3]);
        *reinterpret_cast<ushort4*>(pb + (size_t)p * D_K + 4 * l) = w;
        float s = v[0]*v[0] + v[1]*v[1] + v[2]*v[2] + v[3]*v[3];
#pragma unroll
        for (int m = 32; m >= 1; m >>= 1) s += __shfl_xor(s, m, 64);
        if (l == 0) p2[p] = s;
    } else {
        int row = bid - P_PAD;
        float v[4];
        float mx = -3.4e38f;
#pragma unroll
        for (int i = 0; i < 4; ++i) {
            int c = l + 64 * i;
            v[i] = (c < C_OUT) ? lp[(size_t)row * C_OUT + c] : -3.4e38f;
            mx = fmaxf(mx, v[i]);
        }
#pragma unroll
        for (int m = 32; m >= 1; m >>= 1) mx = fmaxf(mx, __shfl_xor(mx, m, 64));
        float sum = 0.f;
#pragma unroll
        for (int i = 0; i < 4; ++i) {
            int c = l + 64 * i;
            if (c < C_OUT) { v[i] = expf(v[i] - mx); sum += v[i]; }
        }
#pragma unroll
        for (int m = 32; m >= 1; m >>= 1) sum += __shfl_xor(sum, m, 64);
        float inv = 1.f / sum;
#pragma unroll
        for (int i = 0; i < 4; ++i) {
            int c = l + 64 * i;
            if (c < C_OUT) ds[(size_t)row * C_OUT + c] = v[i] * inv;
        }
    }
}

// --- main: pm[b][whh][p0..p0+127] = min over wh-half of (x2 - 2xp) --------
// grid 1024: id = xcd + 8*(q + 4*(grp>>3)), grp = b*2+whh, q = p-quarter
// 4 waves/block, 32 p-rows/wave, double-buffered LDS, 1 barrier/tile,
// VGPR budget engineered for 128 (4 waves/SIMD, 4 blocks/CU)
__global__ __launch_bounds__(256, 4)
void proto_min_kernel(const float* __restrict__ xs,
                      const unsigned short* __restrict__ pb,
                      float* __restrict__ pm) {
    __shared__ unsigned short Xs[2][NT * XS_STRIDE];   // 36864 B
    __shared__ float x2buf[2][8][4][4];                // 1024 B

    const int tid  = threadIdx.x;
    const int wv   = tid >> 6;
    const int lane = tid & 63;
    const int g    = lane >> 4;   // 0..3
    const int lr   = lane & 15;   // 0..15

    const int id  = blockIdx.x;
    const int xcd = id & 7;
    const int t3  = id >> 3;
    const int q   = t3 & 3;                       // p-quarter
    const int grp = ((t3 >> 2) << 3) | xcd;       // 0..255
    const int b   = grp >> 1;
    const int whh = grp & 1;
    const int p0  = q * 128;

    const float* xb = xs + (size_t)b * (D_K * WH) + whh * WHH;

    // A fragments: -2*proto bf16, 32 rows x full K per wave, in registers
    bf16x8 af[2][8];
#pragma unroll
    for (int mf = 0; mf < 2; ++mf) {
        const unsigned short* rp = pb + (size_t)(p0 + 32*wv + 16*mf + lr) * D_K + 8*g;
#pragma unroll
        for (int ks = 0; ks < 8; ++ks)
            af[mf][ks] = *reinterpret_cast<const bf16x8*>(rp + 32*ks);
    }

    const int n4  = tid & 7;    // col-quad within 32-col tile
    const int kq0 = tid >> 3;   // 0..31; k-quads kq0 (half 0) and kq0+32 (half 1)

    float rmin[2][4];
#pragma unroll
    for (int mf = 0; mf < 2; ++mf)
#pragma unroll
        for (int r = 0; r < 4; ++r) rmin[mf][r] = 3.0e38f;

    f32x4 ld[4];        // one half-tile of loads (16 VGPRs)
    f32x4 x2a;          // per-tile x2 partial accumulator

#define LOAD_HALF(T, I) do {                                                  \
        int colb = (T) * NT + 4 * n4;                                         \
        if (colb > WHH - 4) colb = WHH - 4;                                   \
        const float* rowp = xb + (size_t)(4*(kq0 + 32*(I))) * WH + colb;      \
        _Pragma("unroll")                                                     \
        for (int r = 0; r < 4; ++r)                                           \
            ld[r] = *reinterpret_cast<const f32x4*>(rowp + r * WH);           \
    } while (0)

#define STAGE_HALF(I, DST) do {                                               \
        int kq = kq0 + 32*(I);                                                \
        _Pragma("unroll")                                                     \
        for (int r = 0; r < 4; ++r) {                                         \
            f32x4 v = ld[r];                                                  \
            x2a[0] += v[0]*v[0]; x2a[1] += v[1]*v[1];                         \
            x2a[2] += v[2]*v[2]; x2a[3] += v[3]*v[3];                         \
        }                                                                     \
        _Pragma("unroll")                                                     \
        for (int c = 0; c < 4; ++c) {                                         \
            float2 f01 = make_float2(ld[0][c], ld[1][c]);                     \
            float2 f23 = make_float2(ld[2][c], ld[3][c]);                     \
            __hip_bfloat162 b01 = __float22bfloat162_rn(f01);                 \
            __hip_bfloat162 b23 = __float22bfloat162_rn(f23);                 \
            uint2 w;                                                          \
            w.x = *reinterpret_cast<unsigned int*>(&b01);                     \
            w.y = *reinterpret_cast<unsigned int*>(&b23);                     \
            *reinterpret_cast<uint2*>(&Xs[DST][xs_idx(4*n4 + c, 4*kq)]) = w;  \
        }                                                                     \
    } while (0)

#define X2_FINISH(DST) do {                                                   \
        _Pragma("unroll")                                                     \
        for (int c = 0; c < 4; ++c) {                                         \
            x2a[c] += __shfl_xor(x2a[c], 8, 64);                              \
            x2a[c] += __shfl_xor(x2a[c], 16, 64);                             \
            x2a[c] += __shfl_xor(x2a[c], 32, 64);                             \
        }                                                                     \
        if (lane < 8) {                                                       \
            _Pragma("unroll")                                                 \
            for (int c = 0; c < 4; ++c) x2buf[DST][lane][c][wv] = x2a[c];     \
        }                                                                     \
    } while (0)

    // prologue: stage tile 0 into buffer 0
    x2a = (f32x4){0.f, 0.f, 0.f, 0.f};
    LOAD_HALF(0, 0); STAGE_HALF(0, 0);
    LOAD_HALF(0, 1); STAGE_HALF(1, 0);
    X2_FINISH(0);
    __syncthreads();

    for (int t = 0; t < NTILES; ++t) {
        const int cur = t & 1;
        const bool more = (t + 1 < NTILES);

        // T14: issue next tile's half-0 loads (latency hides under MFMA)
        if (more) LOAD_HALF(t + 1, 0);

        // full x2 for this lane's 2 columns (one b128 + 3 adds each)
        float x2v[2];
#pragma unroll
        for (int nf = 0; nf < 2; ++nf) {
            int nn = 16*nf + lr;
            f32x4 qq = *reinterpret_cast<const f32x4*>(&x2buf[cur][nn >> 2][nn & 3][0]);
            x2v[nf] = (qq[0] + qq[1]) + (qq[2] + qq[3]);
        }

        // GEMM with C initialized to x2 (C col = lane&15, same per reg)
        f32x4 acc[2][2];
#pragma unroll
        for (int mf = 0; mf < 2; ++mf)
#pragma unroll
            for (int nf = 0; nf < 2; ++nf)
                acc[mf][nf] = (f32x4){x2v[nf], x2v[nf], x2v[nf], x2v[nf]};

        __builtin_amdgcn_s_setprio(1);
#pragma unroll
        for (int ks = 0; ks < 8; ++ks) {
            bf16x8 bfr[2];
#pragma unroll
            for (int nf = 0; nf < 2; ++nf)
                bfr[nf] = *reinterpret_cast<const bf16x8*>(&Xs[cur][xs_idx(16*nf + lr, 32*ks + 8*g)]);
#pragma unroll
            for (int mf = 0; mf < 2; ++mf)
#pragma unroll
                for (int nf = 0; nf < 2; ++nf)
                    acc[mf][nf] = __builtin_amdgcn_mfma_f32_16x16x32_bf16(
                        af[mf][ks], bfr[nf], acc[mf][nf], 0, 0, 0);
        }
        __builtin_amdgcn_s_setprio(0);

        // stage half-0 into other buffer, then issue half-1 loads
        if (more) {
            x2a = (f32x4){0.f, 0.f, 0.f, 0.f};
            STAGE_HALF(0, cur ^ 1);
            LOAD_HALF(t + 1, 1);
        }

        // running min (covers half-1 load latency)
#pragma unroll
        for (int nf = 0; nf < 2; ++nf)
#pragma unroll
            for (int mf = 0; mf < 2; ++mf)
#pragma unroll
                for (int r = 0; r < 4; ++r)
                    rmin[mf][r] = fminf(rmin[mf][r], acc[mf][nf][r]);

        if (more) {
            STAGE_HALF(1, cur ^ 1);
            X2_FINISH(cur ^ 1);
        }

        __syncthreads();
    }

    // min across the 16 column-lanes (flips only lr bits; g preserved)
#pragma unroll
    for (int mf = 0; mf < 2; ++mf)
#pragma unroll
        for (int r = 0; r < 4; ++r) {
            float v = rmin[mf][r];
#pragma unroll
            for (int m = 1; m <= 8; m <<= 1)
                v = fminf(v, __shfl_xor(v, m, 64));
            rmin[mf][r] = v;
        }

    if (lr == 0) {
        float* pmw = pm + ((size_t)b * 2 + whh) * P_PAD;
#pragma unroll
        for (int mf = 0; mf < 2; ++mf)
#pragma unroll
            for (int r = 0; r < 4; ++r)
                pmw[p0 + 32*wv + 16*mf + 4*g + r] = rmin[mf][r];
    }
#undef LOAD_HALF
#undef STAGE_HALF
#undef X2_FINISH
}

// --- combine halves + exp(-sqrt) + tree path products + pa @ ds -----------
__global__ __launch_bounds__(256)
void out_kernel(const float* __restrict__ pm, const float* __restrict__ p2,
                const float* __restrict__ ds, float* __restrict__ out) {
    __shared__ float sim[NLEAF];
    __shared__ float pa[NLEAF];
    int b = blockIdx.x;
    int t = threadIdx.x;
    const float* pm0 = pm + (size_t)b * 2 * P_PAD;
#pragma unroll
    for (int j = 0; j < 2; ++j) {
        int p = t + 256 * j;
        float m = fminf(pm0[p], pm0[P_PAD + p]);
        float sq = m + p2[p];
        sim[p] = expf(-sqrtf(fabsf(sq) + 1e-14f));
    }
    __syncthreads();
#pragma unroll
    for (int j = 0; j < 2; ++j) {
        int leaf = t + 256 * j;
        int node = 0;
        float prod = 1.f;
#pragma unroll
        for (int st = 0; st < TDEPTH; ++st) {
            int bit = (leaf >> (TDEPTH - 1 - st)) & 1;
            float sv = sim[node];
            prod *= bit ? sv : (1.f - sv);
            node = 2 * node + 1 + bit;
        }
        pa[leaf] = prod;
    }
    __syncthreads();
    if (t < C_OUT) {
        float a0 = 0.f, a1 = 0.f, a2 = 0.f, a3 = 0.f;
        for (int l = 0; l < NLEAF; l += 4) {
            a0 += pa[l + 0] * ds[(size_t)(l + 0) * C_OUT + t];
            a1 += pa[l + 1] * ds[(size_t)(l + 1) * C_OUT + t];
            a2 += pa[l + 2] * ds[(size_t)(l + 2) * C_OUT + t];
            a3 += pa[l + 3] * ds[(size_t)(l + 3) * C_OUT + t];
        }
        out[(size_t)b * C_OUT + t] = (a0 + a1) + (a2 + a3);
    }
}

extern "C" void kernel_launch(void* const* d_in, const int* in_sizes, int n_in,
                              void* d_out, int out_size, void* d_ws, size_t ws_size,
                              hipStream_t stream) {
    (void)in_sizes; (void)n_in; (void)out_size; (void)ws_size;
    const float* xs     = (const float*)d_in[0];
    const float* protos = (const float*)d_in[1];
    const float* lp     = (const float*)d_in[2];
    float* out = (float*)d_out;

    char* ws = (char*)d_ws;
    unsigned short* pb = (unsigned short*)(ws + WS_PROTO);
    float* p2   = (float*)(ws + WS_P2);
    float* pm   = (float*)(ws + WS_PM);
    float* dsm  = (float*)(ws + WS_DS);

    prep2_kernel<<<1024, 64, 0, stream>>>(protos, lp, pb, p2, dsm);
    proto_min_kernel<<<1024, 256, 0, stream>>>(xs, pb, pm);
    out_kernel<<<128, 256, 0, stream>>>(pm, p2, dsm, out);
}

// Round 5
// 71.558 us; speedup vs baseline: 2.2830x; 2.2830x over previous
//
#include <hip/hip_runtime.h>
#include <hip/hip_bf16.h>

typedef __attribute__((ext_vector_type(8))) short bf16x8;
typedef __attribute__((ext_vector_type(4))) float f32x4;

#define D_K    256
#define WH     784
#define WHH    392
#define P_REAL 511
#define P_PAD  512
#define C_OUT  200
#define NLEAF  512
#define TDEPTH 9

#define NT      32
#define NTILES  13          // 12*32 + 8 tail (clamped duplicate columns)
#define XS_STRIDE 288       // ushorts per LDS n-row

// workspace offsets (bytes)
#define WS_PROTO 0
#define WS_P2    (P_PAD*D_K*2)            // 262144
#define WS_PM    (WS_P2 + P_PAD*4)        // 264192  pm[128][2][512] f32
#define WS_DS    (WS_PM + 128*2*P_PAD*4)  // 788480
// total: 788480 + 512*200*4 = 1198080 bytes

static __device__ __forceinline__ unsigned short f2bf(float x) {
    union { float f; unsigned int u; } v; v.f = x;
    unsigned int r = v.u + 0x7FFFu + ((v.u >> 16) & 1u);   // RNE
    return (unsigned short)(r >> 16);
}

// swizzled LDS index (ushort units): XOR row bits into byte bits 4..6;
// bijective per row, keeps 8B-write / 16B-read alignment
static __device__ __forceinline__ int xs_idx(int n, int k) {
    return (n * XS_STRIDE + k) ^ ((n & 0x1C) << 1);
}

// --- fused prep (proto -> bf16(-2p) + p2) and softmax(leaf_params) --------
__global__ __launch_bounds__(64)
void prep2_kernel(const float* __restrict__ protos, const float* __restrict__ lp,
                  unsigned short* __restrict__ pb, float* __restrict__ p2,
                  float* __restrict__ ds) {
    int bid = blockIdx.x;
    int l = threadIdx.x;
    if (bid < P_PAD) {
        int p = bid;
        f32x4 v = {0.f, 0.f, 0.f, 0.f};
        if (p < P_REAL)
            v = *reinterpret_cast<const f32x4*>(protos + (size_t)p * D_K + 4 * l);
        ushort4 w;
        w.x = f2bf(-2.f * v[0]); w.y = f2bf(-2.f * v[1]);
        w.z = f2bf(-2.f * v[2]); w.w = f2bf(-2.f * v[3]);
        *reinterpret_cast<ushort4*>(pb + (size_t)p * D_K + 4 * l) = w;
        float s = v[0]*v[0] + v[1]*v[1] + v[2]*v[2] + v[3]*v[3];
#pragma unroll
        for (int m = 32; m >= 1; m >>= 1) s += __shfl_xor(s, m, 64);
        if (l == 0) p2[p] = s;
    } else {
        int row = bid - P_PAD;
        float v[4];
        float mx = -3.4e38f;
#pragma unroll
        for (int i = 0; i < 4; ++i) {
            int c = l + 64 * i;
            v[i] = (c < C_OUT) ? lp[(size_t)row * C_OUT + c] : -3.4e38f;
            mx = fmaxf(mx, v[i]);
        }
#pragma unroll
        for (int m = 32; m >= 1; m >>= 1) mx = fmaxf(mx, __shfl_xor(mx, m, 64));
        float sum = 0.f;
#pragma unroll
        for (int i = 0; i < 4; ++i) {
            int c = l + 64 * i;
            if (c < C_OUT) { v[i] = expf(v[i] - mx); sum += v[i]; }
        }
#pragma unroll
        for (int m = 32; m >= 1; m >>= 1) sum += __shfl_xor(sum, m, 64);
        float inv = 1.f / sum;
#pragma unroll
        for (int i = 0; i < 4; ++i) {
            int c = l + 64 * i;
            if (c < C_OUT) ds[(size_t)row * C_OUT + c] = v[i] * inv;
        }
    }
}

// --- main: pm[b][whh][p0..p0+127] = min over wh-half of (x2 - 2xp) --------
// grid 1024: id = xcd + 8*(q + 4*(grp>>3)), grp = b*2+whh, q = p-quarter
// 4 waves/block, 32 p-rows/wave, double-buffered LDS, 1 barrier/tile.
// Register budget: af 64 (AGPR-able) + ld 16 + acc 16 + rmin 8 + temps ~45
// = ~150 unified regs -> cap 170 (min 3 waves/EU) fits WITHOUT spilling;
// cap 128 (min 4) provably spills (R4: WRITE_SIZE 40 MB scratch).
__global__ __launch_bounds__(256, 3)
void proto_min_kernel(const float* __restrict__ xs,
                      const unsigned short* __restrict__ pb,
                      float* __restrict__ pm) {
    __shared__ unsigned short Xs[2][NT * XS_STRIDE];   // 36864 B
    __shared__ float x2buf[2][8][4][4];                // 1024 B

    const int tid  = threadIdx.x;
    const int wv   = tid >> 6;
    const int lane = tid & 63;
    const int g    = lane >> 4;   // 0..3
    const int lr   = lane & 15;   // 0..15

    const int id  = blockIdx.x;
    const int xcd = id & 7;
    const int t3  = id >> 3;
    const int q   = t3 & 3;                       // p-quarter
    const int grp = ((t3 >> 2) << 3) | xcd;       // 0..255
    const int b   = grp >> 1;
    const int whh = grp & 1;
    const int p0  = q * 128;

    const float* xb = xs + (size_t)b * (D_K * WH) + whh * WHH;

    // A fragments: -2*proto bf16, 32 rows x full K per wave, in registers
    bf16x8 af[2][8];
#pragma unroll
    for (int mf = 0; mf < 2; ++mf) {
        const unsigned short* rp = pb + (size_t)(p0 + 32*wv + 16*mf + lr) * D_K + 8*g;
#pragma unroll
        for (int ks = 0; ks < 8; ++ks)
            af[mf][ks] = *reinterpret_cast<const bf16x8*>(rp + 32*ks);
    }

    const int n4  = tid & 7;    // col-quad within 32-col tile
    const int kq0 = tid >> 3;   // 0..31; k-quads kq0 (half 0) and kq0+32 (half 1)

    float rmin[2][4];
#pragma unroll
    for (int mf = 0; mf < 2; ++mf)
#pragma unroll
        for (int r = 0; r < 4; ++r) rmin[mf][r] = 3.0e38f;

    f32x4 ld[4];        // one half-tile of loads (16 VGPRs)
    f32x4 x2a;          // per-tile x2 partial accumulator

#define LOAD_HALF(T, I) do {                                                  \
        int colb = (T) * NT + 4 * n4;                                         \
        if (colb > WHH - 4) colb = WHH - 4;                                   \
        const float* rowp = xb + (size_t)(4*(kq0 + 32*(I))) * WH + colb;      \
        _Pragma("unroll")                                                     \
        for (int r = 0; r < 4; ++r)                                           \
            ld[r] = *reinterpret_cast<const f32x4*>(rowp + r * WH);           \
    } while (0)

#define STAGE_HALF(I, DST) do {                                               \
        int kq = kq0 + 32*(I);                                                \
        _Pragma("unroll")                                                     \
        for (int r = 0; r < 4; ++r) {                                         \
            f32x4 v = ld[r];                                                  \
            x2a[0] += v[0]*v[0]; x2a[1] += v[1]*v[1];                         \
            x2a[2] += v[2]*v[2]; x2a[3] += v[3]*v[3];                         \
        }                                                                     \
        _Pragma("unroll")                                                     \
        for (int c = 0; c < 4; ++c) {                                         \
            float2 f01 = make_float2(ld[0][c], ld[1][c]);                     \
            float2 f23 = make_float2(ld[2][c], ld[3][c]);                     \
            __hip_bfloat162 b01 = __float22bfloat162_rn(f01);                 \
            __hip_bfloat162 b23 = __float22bfloat162_rn(f23);                 \
            uint2 w;                                                          \
            w.x = *reinterpret_cast<unsigned int*>(&b01);                     \
            w.y = *reinterpret_cast<unsigned int*>(&b23);                     \
            *reinterpret_cast<uint2*>(&Xs[DST][xs_idx(4*n4 + c, 4*kq)]) = w;  \
        }                                                                     \
    } while (0)

#define X2_FINISH(DST) do {                                                   \
        _Pragma("unroll")                                                     \
        for (int c = 0; c < 4; ++c) {                                         \
            x2a[c] += __shfl_xor(x2a[c], 8, 64);                              \
            x2a[c] += __shfl_xor(x2a[c], 16, 64);                             \
            x2a[c] += __shfl_xor(x2a[c], 32, 64);                             \
        }                                                                     \
        if (lane < 8) {                                                       \
            _Pragma("unroll")                                                 \
            for (int c = 0; c < 4; ++c) x2buf[DST][lane][c][wv] = x2a[c];     \
        }                                                                     \
    } while (0)

    // prologue: stage tile 0 into buffer 0
    x2a = (f32x4){0.f, 0.f, 0.f, 0.f};
    LOAD_HALF(0, 0); STAGE_HALF(0, 0);
    LOAD_HALF(0, 1); STAGE_HALF(1, 0);
    X2_FINISH(0);
    __syncthreads();

    for (int t = 0; t < NTILES; ++t) {
        const int cur = t & 1;
        const bool more = (t + 1 < NTILES);

        // T14: issue next tile's half-0 loads (latency hides under MFMA)
        if (more) LOAD_HALF(t + 1, 0);

        // full x2 for this lane's 2 columns (one b128 + 3 adds each)
        float x2v[2];
#pragma unroll
        for (int nf = 0; nf < 2; ++nf) {
            int nn = 16*nf + lr;
            f32x4 qq = *reinterpret_cast<const f32x4*>(&x2buf[cur][nn >> 2][nn & 3][0]);
            x2v[nf] = (qq[0] + qq[1]) + (qq[2] + qq[3]);
        }

        // GEMM with C initialized to x2 (C col = lane&15, same per reg)
        f32x4 acc[2][2];
#pragma unroll
        for (int mf = 0; mf < 2; ++mf)
#pragma unroll
            for (int nf = 0; nf < 2; ++nf)
                acc[mf][nf] = (f32x4){x2v[nf], x2v[nf], x2v[nf], x2v[nf]};

        __builtin_amdgcn_s_setprio(1);
#pragma unroll
        for (int ks = 0; ks < 8; ++ks) {
            bf16x8 bfr[2];
#pragma unroll
            for (int nf = 0; nf < 2; ++nf)
                bfr[nf] = *reinterpret_cast<const bf16x8*>(&Xs[cur][xs_idx(16*nf + lr, 32*ks + 8*g)]);
#pragma unroll
            for (int mf = 0; mf < 2; ++mf)
#pragma unroll
                for (int nf = 0; nf < 2; ++nf)
                    acc[mf][nf] = __builtin_amdgcn_mfma_f32_16x16x32_bf16(
                        af[mf][ks], bfr[nf], acc[mf][nf], 0, 0, 0);
        }
        __builtin_amdgcn_s_setprio(0);

        // stage half-0 into other buffer, then issue half-1 loads
        if (more) {
            x2a = (f32x4){0.f, 0.f, 0.f, 0.f};
            STAGE_HALF(0, cur ^ 1);
            LOAD_HALF(t + 1, 1);
        }

        // running min (covers half-1 load latency)
#pragma unroll
        for (int nf = 0; nf < 2; ++nf)
#pragma unroll
            for (int mf = 0; mf < 2; ++mf)
#pragma unroll
                for (int r = 0; r < 4; ++r)
                    rmin[mf][r] = fminf(rmin[mf][r], acc[mf][nf][r]);

        if (more) {
            STAGE_HALF(1, cur ^ 1);
            X2_FINISH(cur ^ 1);
        }

        __syncthreads();
    }

    // min across the 16 column-lanes (flips only lr bits; g preserved)
#pragma unroll
    for (int mf = 0; mf < 2; ++mf)
#pragma unroll
        for (int r = 0; r < 4; ++r) {
            float v = rmin[mf][r];
#pragma unroll
            for (int m = 1; m <= 8; m <<= 1)
                v = fminf(v, __shfl_xor(v, m, 64));
            rmin[mf][r] = v;
        }

    if (lr == 0) {
        float* pmw = pm + ((size_t)b * 2 + whh) * P_PAD;
#pragma unroll
        for (int mf = 0; mf < 2; ++mf)
#pragma unroll
            for (int r = 0; r < 4; ++r)
                pmw[p0 + 32*wv + 16*mf + 4*g + r] = rmin[mf][r];
    }
#undef LOAD_HALF
#undef STAGE_HALF
#undef X2_FINISH
}

// --- combine halves + exp(-sqrt) + tree path products + pa @ ds -----------
__global__ __launch_bounds__(256)
void out_kernel(const float* __restrict__ pm, const float* __restrict__ p2,
                const float* __restrict__ ds, float* __restrict__ out) {
    __shared__ float sim[NLEAF];
    __shared__ float pa[NLEAF];
    int b = blockIdx.x;
    int t = threadIdx.x;
    const float* pm0 = pm + (size_t)b * 2 * P_PAD;
#pragma unroll
    for (int j = 0; j < 2; ++j) {
        int p = t + 256 * j;
        float m = fminf(pm0[p], pm0[P_PAD + p]);
        float sq = m + p2[p];
        sim[p] = expf(-sqrtf(fabsf(sq) + 1e-14f));
    }
    __syncthreads();
#pragma unroll
    for (int j = 0; j < 2; ++j) {
        int leaf = t + 256 * j;
        int node = 0;
        float prod = 1.f;
#pragma unroll
        for (int st = 0; st < TDEPTH; ++st) {
            int bit = (leaf >> (TDEPTH - 1 - st)) & 1;
            float sv = sim[node];
            prod *= bit ? sv : (1.f - sv);
            node = 2 * node + 1 + bit;
        }
        pa[leaf] = prod;
    }
    __syncthreads();
    if (t < C_OUT) {
        float a0 = 0.f, a1 = 0.f, a2 = 0.f, a3 = 0.f;
        for (int l = 0; l < NLEAF; l += 4) {
            a0 += pa[l + 0] * ds[(size_t)(l + 0) * C_OUT + t];
            a1 += pa[l + 1] * ds[(size_t)(l + 1) * C_OUT + t];
            a2 += pa[l + 2] * ds[(size_t)(l + 2) * C_OUT + t];
            a3 += pa[l + 3] * ds[(size_t)(l + 3) * C_OUT + t];
        }
        out[(size_t)b * C_OUT + t] = (a0 + a1) + (a2 + a3);
    }
}

extern "C" void kernel_launch(void* const* d_in, const int* in_sizes, int n_in,
                              void* d_out, int out_size, void* d_ws, size_t ws_size,
                              hipStream_t stream) {
    (void)in_sizes; (void)n_in; (void)out_size; (void)ws_size;
    const float* xs     = (const float*)d_in[0];
    const float* protos = (const float*)d_in[1];
    const float* lp     = (const float*)d_in[2];
    float* out = (float*)d_out;

    char* ws = (char*)d_ws;
    unsigned short* pb = (unsigned short*)(ws + WS_PROTO);
    float* p2   = (float*)(ws + WS_P2);
    float* pm   = (float*)(ws + WS_PM);
    float* dsm  = (float*)(ws + WS_DS);

    prep2_kernel<<<1024, 64, 0, stream>>>(protos, lp, pb, p2, dsm);
    proto_min_kernel<<<1024, 256, 0, stream>>>(xs, pb, pm);
    out_kernel<<<128, 256, 0, stream>>>(pm, p2, dsm, out);
}